// Round 11
// baseline (205.035 us; speedup 1.0000x reference)
//
#include <hip/hip_runtime.h>

// Problem constants (B, T, IN, H, OUT) = (256, 128, 128, 256, 128)
// External tensors f32; gx workspace bf16 PRE-SCALED by log2e / 2*log2e.
//
// Round-16: R10's 512-thr scan regressed because hipcc's occupancy heuristic
// (no launch_bounds 2nd arg) capped regs at 80 and REMATERIALIZED the 96-reg
// fragment file from global every step (L2-served -> invisible in FETCH_SIZE;
// VGPR_Count=80 + WRITE=768KB was the tell). Third face of the register wall
// (R2/R4 spill, R10 remat).
// This round is no-lose: compile BOTH
//   cru_scan512  = R10 structure + __launch_bounds__(512,1)  (256-reg budget)
//   cru_scan1024 = R9's proven 93.5us kernel (frag base remapped to the
//                  shared 512-layout whp8: tp=((tid>>7)<<6)|(tid&63), s=(tid>>6)&1)
// and select at launch via hipFuncGetAttributes().numRegs >= 140 (resident
// fragment file) -- host-side, graph-capture-safe, cached in a static.
#define B_   256
#define T_   128
#define IN_  128
#define H_   256
#define H3_  768
#define OUT_ 128

#define L2E  1.4426950408889634f

typedef unsigned short u16;
typedef u16   u16x4  __attribute__((ext_vector_type(4)));
typedef u16   u16x8  __attribute__((ext_vector_type(8)));
typedef __bf16 bf16x8 __attribute__((ext_vector_type(8)));
typedef float f32x4  __attribute__((ext_vector_type(4)));
typedef int   i32x4  __attribute__((ext_vector_type(4)));
typedef signed char c8x8 __attribute__((ext_vector_type(8)));

__device__ __forceinline__ float bf2f(u16 u) {
  unsigned int v = ((unsigned int)u) << 16;
  return __builtin_bit_cast(float, v);
}
__device__ __forceinline__ u16 f2bf(float f) {        // RNE (off hot path)
  unsigned int u = __builtin_bit_cast(unsigned int, f);
  u += 0x7fffu + ((u >> 16) & 1u);
  return (u16)(u >> 16);
}
__device__ __forceinline__ f32x4 mfma16(bf16x8 a, bf16x8 b, f32x4 c) {
  return __builtin_amdgcn_mfma_f32_16x16x32_bf16(a, b, c, 0, 0, 0);
}
__device__ __forceinline__ i32x4 mfma8(i32x4 a, i32x4 b, i32x4 c) {
  return __builtin_amdgcn_mfma_i32_16x16x64_i8(a, b, c, 0, 0, 0);
}
__device__ __forceinline__ float exp2f_(float x) {
#if __has_builtin(__builtin_amdgcn_exp2f)
  return __builtin_amdgcn_exp2f(x);
#else
  return __builtin_exp2f(x);
#endif
}
__device__ __forceinline__ float rcp_(float x) { return __builtin_amdgcn_rcpf(x); }

__device__ __forceinline__ int pick4i(i32x4 v, int e) {
  int r = v[0];
  r = (e == 1) ? v[1] : r;
  r = (e == 2) ? v[2] : r;
  r = (e == 3) ? v[3] : r;
  return r;
}

// ---------------------------------------------------------------------------
// K1 (prep0): blocks [0,96): Wx (f32, 128x768) -> WxT (bf16, 768x128)
//             blocks [96,108): sW[n] = max_k |Wh[k,n]| / 127
__global__ __launch_bounds__(1024) void prep0(const float* __restrict__ Wx,
                                              const float* __restrict__ Wh,
                                              u16* __restrict__ WxT,
                                              float* __restrict__ sw) {
  const int bid = blockIdx.x;
  if (bid < 96) {
    int o = bid * 1024 + threadIdx.x;           // 0..98303
    int n = o >> 7, k = o & 127;
    WxT[o] = f2bf(Wx[(size_t)k * H3_ + n]);
  } else {
    __shared__ float red[16][64];
    const int n0 = (bid - 96) * 64;             // 12 blocks cover 768 cols
    const int nl = threadIdx.x & 63, kg = threadIdx.x >> 6;   // 16 k-groups
    float m = 1e-30f;
    #pragma unroll
    for (int i = 0; i < 16; ++i)
      m = fmaxf(m, fabsf(Wh[(size_t)(kg * 16 + i) * H3_ + n0 + nl]));
    red[kg][nl] = m;
    __syncthreads();
    if (threadIdx.x < 64) {
      float v = m;                              // kg==0 partial
      #pragma unroll
      for (int i = 1; i < 16; ++i) v = fmaxf(v, red[i][nl]);
      sw[n0 + nl] = v * (1.f / 127.f);
    }
  }
}

// ---------------------------------------------------------------------------
// K2 (prep1): blocks [0,48):   Wh -> whp8 int8 pack, 512-consumer layout:
//   whp8[tp*384 + g*128 + s*64 + kk*16 + j8*8 + j],
//   n = g*256 + (tp>>6)*32 + s*16 + (tp&15), k = kk*64 + quad*16 + j8*8 + j.
//             blocks [48,560): gx GEMM, tile 128(M) x 384(N), K=128.
__global__ __launch_bounds__(512) void prep1(const float* __restrict__ x,
                                             const u16* __restrict__ WxT,
                                             const float* __restrict__ bx,
                                             const float* __restrict__ bh,
                                             const float* __restrict__ Wh,
                                             const float* __restrict__ sw,
                                             u16* __restrict__ gxw,
                                             signed char* __restrict__ whp8) {
  __shared__ __align__(16) char smem[(128 * 136 + 384 * 136) * 2];  // 139 KB
  const int bid = blockIdx.x;
  const int tid = threadIdx.x;

  if (bid < 48) {                               // ---- Wh int8 pack ----
    int o8 = bid * 512 + tid;                   // 0..24575 (8 bytes each)
    int tp  = o8 / 48;                          // 512-scan tid, 0..511
    int idx = o8 % 48;                          // [g][s][kk][j8]
    int g  = idx >> 4;
    int s  = (idx >> 3) & 1;
    int kk = (idx >> 1) & 3;
    int j8 = idx & 1;
    int l  = tp & 63, w = tp >> 6;
    int n  = g * 256 + w * 32 + s * 16 + (l & 15);
    int kbase = kk * 64 + ((l >> 4) & 3) * 16 + j8 * 8;
    float rs = rcp_(sw[n]);                     // 127 / max_k|Wh[:,n]|
    c8x8 v;
    #pragma unroll
    for (int j = 0; j < 8; ++j) {
      float q = __builtin_rintf(Wh[(size_t)(kbase + j) * H3_ + n] * rs);
      v[j] = (signed char)(int)q;
    }
    *(c8x8*)(whp8 + (size_t)o8 * 8) = v;
    return;
  }

  // ---- gx GEMM ----
  u16 (*As)[136] = (u16(*)[136])smem;
  u16 (*Bs)[136] = (u16(*)[136])(smem + 128 * 136 * 2);
  u16 (*St)[392] = (u16(*)[392])smem;           // aliases after 2nd barrier

  const int gb = bid - 48;                      // 0..511
  const int mt = gb & 255;
  const int n0 = (gb >> 8) * 384;               // 0 or 384
  const int m0 = mt * 128;
  const int t  = mt >> 1;
  const int brow0 = (mt & 1) * 128;
  const int w = tid >> 6, lane = tid & 63, quad = lane >> 4, r = lane & 15;
  const int wm = w >> 2, wn = w & 3;            // 2 x 4 wave grid

  {  // A tile: 128 rows x 128 cols, f32 -> bf16; 4-lane groups read 64B
    int row = tid >> 2;
    int colc = (tid & 3) * 4;
    const float* s = x + ((size_t)(brow0 + row) * T_ + t) * IN_ + colc;
    #pragma unroll
    for (int c4 = 0; c4 < 8; ++c4) {
      f32x4 v = *(const f32x4*)(s + c4 * 16);
      u16x4 b;
      b[0] = f2bf(v[0]); b[1] = f2bf(v[1]); b[2] = f2bf(v[2]); b[3] = f2bf(v[3]);
      *(u16x4*)&As[row][colc + c4 * 16] = b;
    }
  }
  {  // B tile [n][k] from WxT: 384 x 128 u16
    #pragma unroll
    for (int i = 0; i < 12; ++i) {
      int idx = tid + i * 512;                  // 0..6143
      int row = idx >> 4, col8 = (idx & 15) * 8;
      *(u16x8*)&Bs[row][col8] = *(const u16x8*)(WxT + (size_t)(n0 + row) * IN_ + col8);
    }
  }
  __syncthreads();

  f32x4 acc[4][6];
  #pragma unroll
  for (int i = 0; i < 4; ++i)
    #pragma unroll
    for (int j = 0; j < 6; ++j)
      acc[i][j] = (f32x4){0.f, 0.f, 0.f, 0.f};

  #pragma unroll
  for (int kk = 0; kk < 4; ++kk) {
    bf16x8 a[4];
    #pragma unroll
    for (int m2 = 0; m2 < 4; ++m2)
      a[m2] = *(const bf16x8*)&As[wm * 64 + m2 * 16 + r][kk * 32 + quad * 8];
    #pragma unroll
    for (int n2 = 0; n2 < 6; ++n2) {
      bf16x8 b = *(const bf16x8*)&Bs[wn * 96 + n2 * 16 + r][kk * 32 + quad * 8];
      #pragma unroll
      for (int m2 = 0; m2 < 4; ++m2)
        acc[m2][n2] = mfma16(a[m2], b, acc[m2][n2]);
    }
  }

  __syncthreads();   // all LDS reads done; safe to alias As/Bs as St

  #pragma unroll
  for (int m2 = 0; m2 < 4; ++m2)
    #pragma unroll
    for (int n2 = 0; n2 < 6; ++n2) {
      int nl = wn * 96 + n2 * 16 + r;           // local col (C col = lane&15)
      int n  = n0 + nl;
      float sc = (n < 512) ? L2E : (2.f * L2E);
      float bias = bx[n] + (n < 512 ? bh[n] : 0.f);
      #pragma unroll
      for (int e = 0; e < 4; ++e) {             // C row = quad*4 + e
        int mrow = wm * 64 + m2 * 16 + quad * 4 + e;
        St[mrow][nl] = f2bf((acc[m2][n2][e] + bias) * sc);
      }
    }
  __syncthreads();

  #pragma unroll
  for (int i = 0; i < 12; ++i) {                // coalesced 16B stores
    int idx = tid + i * 512;                    // 0..6143
    int row = idx / 48, c8 = (idx % 48) * 8;
    *(u16x8*)(gxw + (size_t)(m0 + row) * H3_ + n0 + c8) = *(const u16x8*)&St[row][c8];
  }
}

// ---------------------------------------------------------------------------
// K3a: scan, 512 threads (8 waves), launch_bounds(512,1) -> 256-arch-VGPR
// budget so the 96-reg frag file + 6 accs + eager frags stay RESIDENT.
// Selected at launch only if numRegs >= 140 (residency check).
__global__ __launch_bounds__(512, 1)
void cru_scan512(const float* __restrict__ hid,
                 const signed char* __restrict__ whp8,
                 const float* __restrict__ sw,
                 const float* __restrict__ bh,
                 const u16*  __restrict__ gx,
                 float* __restrict__ hT) {
  __shared__ __align__(16) signed char h8[2][4][288];   // double buffer, 2.3 KB

  const int bid = blockIdx.x;           // 192 blocks
  const int c   = bid >> 6;             // component 0..2
  const int b0  = (bid & 63) << 2;      // batch row group of 4
  const int tid = threadIdx.x;
  const int lane = tid & 63, quad = lane >> 4, m = lane & 15;
  const int w  = tid >> 6;              // wave 0..7
  const int bb = m & 3;                 // batch row within group
  const int e  = m >> 2;                // kept accumulator element
  const int hcol0 = w * 32 + quad * 4 + e;      // owned n-col, s=0
  const int hcol1 = hcol0 + 16;                 // owned n-col, s=1

  // --- one-time fragment load: 384 B contiguous per thread, coalesced ---
  i32x4 bfr[3][2][4];                   // [g][s][kk]
  {
    const signed char* wp = whp8 + (size_t)tid * 384;
    #pragma unroll
    for (int g = 0; g < 3; ++g)
      #pragma unroll
      for (int s = 0; s < 2; ++s)
        #pragma unroll
        for (int kk = 0; kk < 4; ++kk)
          bfr[g][s][kk] = *(const i32x4*)(wp + g * 128 + s * 64 + kk * 16);
  }

  // --- dequant constants: gh = acc * sW/127, then gate prescale ---
  const float dqR0 = sw[hcol0]       * (L2E / 127.f);
  const float dqR1 = sw[hcol1]       * (L2E / 127.f);
  const float dqZ0 = sw[256 + hcol0] * (L2E / 127.f);
  const float dqZ1 = sw[256 + hcol1] * (L2E / 127.f);
  const float dqN0 = sw[512 + hcol0] * (2.f * L2E / 127.f);
  const float dqN1 = sw[512 + hcol1] * (2.f * L2E / 127.f);

  // --- this lane's h elements ---
  const size_t hrow0 = (size_t)(c * 256 + b0 + bb) * 256 + hcol0;
  float hx0 = hid[hrow0];
  float hx1 = hid[hrow0 + 16];
  h8[0][bb][hcol0] = (signed char)(int)__builtin_rintf(fminf(fmaxf(hx0, -1.f), 1.f) * 127.f);
  h8[0][bb][hcol1] = (signed char)(int)__builtin_rintf(fminf(fmaxf(hx1, -1.f), 1.f) * 127.f);
  const float bn0 = bh[512 + hcol0] * (2.f * L2E);
  const float bn1 = bh[512 + hcol1] * (2.f * L2E);

  const u16* gxp = gx + (size_t)(b0 + bb) * H3_ + hcol0;
  const int rbase = bb * 288 + quad * 16;      // B-frag read base (bytes)

  u16 xr0 = gxp[0],   xr1 = gxp[16];
  u16 xz0 = gxp[256], xz1 = gxp[272];
  u16 xn0 = gxp[512], xn1 = gxp[528];
  const u16* gxs = gxp + (size_t)(B_ * H3_);   // points at t+1

  __syncthreads();

  #pragma unroll 2
  for (int t = 0; t < T_; ++t) {
    const int sel = t & 1;

    // A) eager B-frag reads (shared by all 6 accumulator chains)
    const signed char* hb = &h8[sel][0][0];
    i32x4 f0 = *(const i32x4*)(hb + rbase);
    i32x4 f1 = *(const i32x4*)(hb + rbase + 64);
    i32x4 f2 = *(const i32x4*)(hb + rbase + 128);
    i32x4 f3 = *(const i32x4*)(hb + rbase + 192);

    // B) kk-major MFMA: 6 independent accumulator chains interleaved
    __builtin_amdgcn_s_setprio(1);
    i32x4 aR0 = {0,0,0,0}, aR1 = {0,0,0,0};
    i32x4 aZ0 = {0,0,0,0}, aZ1 = {0,0,0,0};
    i32x4 aN0 = {0,0,0,0}, aN1 = {0,0,0,0};
#define STEP_(kk, fk) \
    aR0 = mfma8(bfr[0][0][kk], fk, aR0); \
    aR1 = mfma8(bfr[0][1][kk], fk, aR1); \
    aZ0 = mfma8(bfr[1][0][kk], fk, aZ0); \
    aZ1 = mfma8(bfr[1][1][kk], fk, aZ1); \
    aN0 = mfma8(bfr[2][0][kk], fk, aN0); \
    aN1 = mfma8(bfr[2][1][kk], fk, aN1);
    STEP_(0, f0)
    STEP_(1, f1)
    STEP_(2, f2)
    STEP_(3, f3)
#undef STEP_
    __builtin_amdgcn_s_setprio(0);

    // C) unconditional gx(t+1) prefetch (t=127 lands in mapped ws)
    u16 nr0 = gxs[0],   nr1 = gxs[16];
    u16 nz0 = gxs[256], nz1 = gxs[272];
    u16 nn0_ = gxs[512], nn1_ = gxs[528];
    gxs += B_ * H3_;

    // D) epilogue, s=0 column
    {
      float gR = (float)pick4i(aR0, e) * dqR0;
      float gZ = (float)pick4i(aZ0, e) * dqZ0;
      float sr = rcp_(1.f + exp2f_(-(bf2f(xr0) + gR)));
      float sz = rcp_(1.f + exp2f_(-(bf2f(xz0) + gZ)));
      float gN = (float)pick4i(aN0, e) * dqN0;
      float nv = bf2f(xn0) + sr * (gN + bn0);              // 2*L2E-scaled
      float nn = fmaf(2.f, rcp_(1.f + exp2f_(-nv)), -1.f); // tanh
      float hv = nn + sz * (hx0 - nn);
      hx0 = hv;
      h8[sel ^ 1][bb][hcol0] = (signed char)(int)__builtin_rintf(hv * 127.f);
    }
    // E) epilogue, s=1 column
    {
      float gR = (float)pick4i(aR1, e) * dqR1;
      float gZ = (float)pick4i(aZ1, e) * dqZ1;
      float sr = rcp_(1.f + exp2f_(-(bf2f(xr1) + gR)));
      float sz = rcp_(1.f + exp2f_(-(bf2f(xz1) + gZ)));
      float gN = (float)pick4i(aN1, e) * dqN1;
      float nv = bf2f(xn1) + sr * (gN + bn1);
      float nn = fmaf(2.f, rcp_(1.f + exp2f_(-nv)), -1.f);
      float hv = nn + sz * (hx1 - nn);
      hx1 = hv;
      h8[sel ^ 1][bb][hcol1] = (signed char)(int)__builtin_rintf(hv * 127.f);
    }
    xr0 = nr0; xr1 = nr1; xz0 = nz0; xz1 = nz1; xn0 = nn0_; xn1 = nn1_;
    __syncthreads();   // h8[sel^1] ready; orders next-step reads of sel
  }

  hT[hrow0] = hx0;
  hT[hrow0 + 16] = hx1;
}

// ---------------------------------------------------------------------------
// K3b: scan, 1024 threads — R9's proven 93.5us kernel, fallback path.
// Frag base remapped to the shared 512-layout whp8:
//   tp = ((tid>>7)<<6)|(tid&63), s = (tid>>6)&1 (w16 = 2*w8 + s).
__global__ __launch_bounds__(1024)
void cru_scan1024(const float* __restrict__ hid,
                  const signed char* __restrict__ whp8,
                  const float* __restrict__ sw,
                  const float* __restrict__ bh,
                  const u16*  __restrict__ gx,
                  float* __restrict__ hT) {
  __shared__ __align__(16) signed char h8[2][4][288];   // double buffer, 2.3 KB

  const int bid = blockIdx.x;           // 192 blocks
  const int c   = bid >> 6;             // component 0..2
  const int b0  = (bid & 63) << 2;      // batch row group of 4
  const int tid = threadIdx.x;
  const int lane = tid & 63, quad = lane >> 4, m = lane & 15;
  const int w  = tid >> 6;              // wave 0..15
  const int bb = m & 3;                 // batch row within group
  const int e  = m >> 2;                // kept accumulator element
  const int hcol = w * 16 + quad * 4 + e;   // owned n-col 0..255

  // --- one-time fragment load from 512-layout whp8 ---
  i32x4 bfr[3][4];
  {
    const signed char* wp = whp8
        + (size_t)(((tid >> 7) << 6) | (tid & 63)) * 384
        + (size_t)((tid >> 6) & 1) * 64;
    #pragma unroll
    for (int g = 0; g < 3; ++g)
      #pragma unroll
      for (int kk = 0; kk < 4; ++kk)
        bfr[g][kk] = *(const i32x4*)(wp + g * 128 + kk * 16);
  }

  // --- dequant constants: gh = acc * sW/127, then gate prescale ---
  const float dqR = sw[hcol]       * (L2E / 127.f);
  const float dqZ = sw[256 + hcol] * (L2E / 127.f);
  const float dqN = sw[512 + hcol] * (2.f * L2E / 127.f);

  // --- this lane's h element: h[bb][hcol] ---
  const size_t hrow = (size_t)(c * 256 + b0 + bb) * 256 + hcol;
  float hx = hid[hrow];
  h8[0][bb][hcol] = (signed char)(int)__builtin_rintf(fminf(fmaxf(hx, -1.f), 1.f) * 127.f);
  const float bn0 = bh[512 + hcol] * (2.f * L2E);

  const u16* gxp = gx + (size_t)(b0 + bb) * H3_ + hcol;
  const int rbase = bb * 288 + quad * 16;      // B-frag read base (bytes)

  u16 xr = gxp[0], xz = gxp[256], xn = gxp[512];
  const u16* gxs = gxp + (size_t)(B_ * H3_);   // points at t+1

  __syncthreads();

  #pragma unroll 2
  for (int t = 0; t < T_; ++t) {
    const int sel = t & 1;

    // A) eager B-frag reads (4 x ds_read_b128, 4-way broadcast)
    const signed char* hb = &h8[sel][0][0];
    i32x4 f0 = *(const i32x4*)(hb + rbase);
    i32x4 f1 = *(const i32x4*)(hb + rbase + 64);
    i32x4 f2 = *(const i32x4*)(hb + rbase + 128);
    i32x4 f3 = *(const i32x4*)(hb + rbase + 192);

    // B) kk-major MFMA: 3 independent accumulator chains interleaved
    __builtin_amdgcn_s_setprio(1);
    i32x4 accR = {0, 0, 0, 0};
    i32x4 accZ = {0, 0, 0, 0};
    i32x4 accN = {0, 0, 0, 0};
    accR = mfma8(bfr[0][0], f0, accR);
    accZ = mfma8(bfr[1][0], f0, accZ);
    accN = mfma8(bfr[2][0], f0, accN);
    accR = mfma8(bfr[0][1], f1, accR);
    accZ = mfma8(bfr[1][1], f1, accZ);
    accN = mfma8(bfr[2][1], f1, accN);
    accR = mfma8(bfr[0][2], f2, accR);
    accZ = mfma8(bfr[1][2], f2, accZ);
    accN = mfma8(bfr[2][2], f2, accN);
    accR = mfma8(bfr[0][3], f3, accR);
    accZ = mfma8(bfr[1][3], f3, accZ);
    accN = mfma8(bfr[2][3], f3, accN);
    __builtin_amdgcn_s_setprio(0);

    // C) unconditional gx(t+1) prefetch
    u16 nxr = gxs[0], nxz = gxs[256], nxn = gxs[512];
    gxs += B_ * H3_;

    // D) r/z sigmoids
    float gR = (float)pick4i(accR, e) * dqR;
    float gZ = (float)pick4i(accZ, e) * dqZ;
    float sr = rcp_(1.f + exp2f_(-(bf2f(xr) + gR)));       // sigmoid
    float sz = rcp_(1.f + exp2f_(-(bf2f(xz) + gZ)));

    // E) tanh + GRU update
    float gN = (float)pick4i(accN, e) * dqN;
    float nv = bf2f(xn) + sr * (gN + bn0);                 // 2*L2E-scaled
    float nn = fmaf(2.f, rcp_(1.f + exp2f_(-nv)), -1.f);   // tanh, inf-safe
    float hv = nn + sz * (hx - nn);
    hx = hv;
    h8[sel ^ 1][bb][hcol] = (signed char)(int)__builtin_rintf(hv * 127.f);
    xr = nxr; xz = nxz; xn = nxn;
    __syncthreads();   // h8[sel^1] ready; orders next-step reads of sel
  }

  hT[hrow] = hx;
}

// ---------------------------------------------------------------------------
// K4: out[b] = elu(sum_c hT[c,b,:] @ Wf + bf); feature[c,:] = mean_b hT
__global__ __launch_bounds__(128) void finalize(const float* __restrict__ hT,
                                                const float* __restrict__ Wf,
                                                const float* __restrict__ bfv,
                                                float* __restrict__ out) {
  __shared__ float hsum[256];
  const int bid = blockIdx.x, tid = threadIdx.x;
  if (bid < 256) {
    const int b = bid;
    for (int k = tid; k < 256; k += 128)
      hsum[k] = hT[((size_t)(0 * 256 + b)) * 256 + k]
              + hT[((size_t)(1 * 256 + b)) * 256 + k]
              + hT[((size_t)(2 * 256 + b)) * 256 + k];
    __syncthreads();
    float acc = bfv[tid];
    #pragma unroll 8
    for (int k = 0; k < 256; ++k)
      acc = fmaf(hsum[k], Wf[(size_t)k * OUT_ + tid], acc);
    float rv = acc > 0.f ? acc : (__expf(acc) - 1.f);
    out[b * OUT_ + tid] = rv;
  } else {
    const int idx = bid - 256;                 // 0..5
    const int c = idx >> 1, j = ((idx & 1) << 7) + tid;
    float sum = 0.f;
    #pragma unroll 4
    for (int b = 0; b < 256; ++b)
      sum += hT[((size_t)(c * 256 + b)) * 256 + j];
    out[B_ * OUT_ + c * 256 + j] = sum * (1.f / 256.f);
  }
}

// ---------------------------------------------------------------------------
extern "C" void kernel_launch(void* const* d_in, const int* in_sizes, int n_in,
                              void* d_out, int out_size, void* d_ws, size_t ws_size,
                              hipStream_t stream) {
  const float* x   = (const float*)d_in[0];
  const float* hid = (const float*)d_in[1];
  const float* Wx  = (const float*)d_in[2];
  const float* bx  = (const float*)d_in[3];
  const float* Wh  = (const float*)d_in[4];
  const float* bh  = (const float*)d_in[5];
  const float* Wf  = (const float*)d_in[6];
  const float* bf_ = (const float*)d_in[7];
  float* out = (float*)d_out;

  char* ws = (char*)d_ws;
  u16* WxT   = (u16*)ws;                                   // 768*128 bf16 = 192 KiB
  u16* gxw   = (u16*)(ws + (1 << 18));                     // 48 MiB
  size_t off = (1 << 18) + (size_t)T_ * B_ * H3_ * 2;
  float* hTw = (float*)(ws + off);                         // 3*256*256 f32 = 768 KiB
  off += (size_t)3 * 256 * 256 * 4;
  signed char* whp8 = (signed char*)(ws + off);            // 512*384 = 192 KiB
  off += (size_t)512 * 384;
  float* sww = (float*)(ws + off);                         // 768 f32

  // Residency check (host-side, graph-capture-safe, cached): launch the
  // 512-thread scan only if its fragment file compiled register-resident.
  static int scan_variant = -1;
  if (scan_variant < 0) {
    hipFuncAttributes attr;
    scan_variant = 0;
    if (hipFuncGetAttributes(&attr, (const void*)cru_scan512) == hipSuccess &&
        attr.numRegs >= 140)
      scan_variant = 1;
  }

  prep0<<<108, 1024, 0, stream>>>(Wx, Wh, WxT, sww);
  prep1<<<560, 512, 0, stream>>>(x, WxT, bx, bh, Wh, sww, gxw, whp8);
  if (scan_variant == 1)
    cru_scan512<<<192, 512, 0, stream>>>(hid, whp8, sww, bh, gxw, hTw);
  else
    cru_scan1024<<<192, 1024, 0, stream>>>(hid, whp8, sww, bh, gxw, hTw);
  finalize<<<262, 128, 0, stream>>>(hTw, Wf, bf_, out);
}

// Round 12
// 196.384 us; speedup vs baseline: 1.0440x; 1.0440x over previous
//
#include <hip/hip_runtime.h>

// Problem constants (B, T, IN, H, OUT) = (256, 128, 128, 256, 128)
// External tensors f32; gx workspace bf16 PRE-SCALED by log2e / 2*log2e.
//
// Round-17: restore the session-best configuration (R9: scan 93.5us, total
// 194.5us) and stop fighting the register wall. R10/R11 established:
//  - hipcc caps the 512-thr scan at 80 arch VGPRs (remat of the frag file)
//    regardless of __launch_bounds__(512,1); hipFuncGetAttributes.numRegs
//    counts the unified file, so a numRegs-based residency probe misfires.
//  - Halving the LDS stream gave 0: it was already hidden. R9's counters
//    (MfmaUtil 46% + VALUBusy 53% active ~ 100%) show the barrier-locked
//    phases are serialized but saturated -> 93.5us is this decomposition's
//    practical floor.
// This file = R9 exactly (scan + matching whp8 1024-consumer pack layout),
// plus ONE low-risk fix: prep0's Wx transpose now reads coalesced
// (consecutive lanes = consecutive n, f32x4) and scatters the u16 WRITES
// (L2-absorbed) instead of scattering the reads.
#define B_   256
#define T_   128
#define IN_  128
#define H_   256
#define H3_  768
#define OUT_ 128

#define L2E  1.4426950408889634f

typedef unsigned short u16;
typedef u16   u16x4  __attribute__((ext_vector_type(4)));
typedef u16   u16x8  __attribute__((ext_vector_type(8)));
typedef __bf16 bf16x8 __attribute__((ext_vector_type(8)));
typedef float f32x4  __attribute__((ext_vector_type(4)));
typedef int   i32x4  __attribute__((ext_vector_type(4)));
typedef signed char c8x8 __attribute__((ext_vector_type(8)));

__device__ __forceinline__ float bf2f(u16 u) {
  unsigned int v = ((unsigned int)u) << 16;
  return __builtin_bit_cast(float, v);
}
__device__ __forceinline__ u16 f2bf(float f) {        // RNE (off hot path)
  unsigned int u = __builtin_bit_cast(unsigned int, f);
  u += 0x7fffu + ((u >> 16) & 1u);
  return (u16)(u >> 16);
}
__device__ __forceinline__ f32x4 mfma16(bf16x8 a, bf16x8 b, f32x4 c) {
  return __builtin_amdgcn_mfma_f32_16x16x32_bf16(a, b, c, 0, 0, 0);
}
__device__ __forceinline__ i32x4 mfma8(i32x4 a, i32x4 b, i32x4 c) {
  return __builtin_amdgcn_mfma_i32_16x16x64_i8(a, b, c, 0, 0, 0);
}
__device__ __forceinline__ float exp2f_(float x) {
#if __has_builtin(__builtin_amdgcn_exp2f)
  return __builtin_amdgcn_exp2f(x);
#else
  return __builtin_exp2f(x);
#endif
}
__device__ __forceinline__ float rcp_(float x) { return __builtin_amdgcn_rcpf(x); }

__device__ __forceinline__ int pick4i(i32x4 v, int e) {
  int r = v[0];
  r = (e == 1) ? v[1] : r;
  r = (e == 2) ? v[2] : r;
  r = (e == 3) ? v[3] : r;
  return r;
}

// ---------------------------------------------------------------------------
// K1 (prep0): blocks [0,24): Wx (f32, 128x768) -> WxT (bf16, 768x128).
//   COALESCED READS: thread handles 4 consecutive n of one k-row (f32x4);
//   the u16 writes scatter (stride 256B) and are absorbed by L2.
//             blocks [24,36): sW[n] = max_k |Wh[k,n]| / 127
__global__ __launch_bounds__(1024) void prep0(const float* __restrict__ Wx,
                                              const float* __restrict__ Wh,
                                              u16* __restrict__ WxT,
                                              float* __restrict__ sw) {
  const int bid = blockIdx.x;
  if (bid < 24) {
    int idx = bid * 1024 + threadIdx.x;         // 0..24575
    int k   = idx / 192;                        // 0..127
    int n4  = (idx % 192) * 4;                  // 0..764
    f32x4 v = *(const f32x4*)(Wx + (size_t)k * H3_ + n4);
    #pragma unroll
    for (int j = 0; j < 4; ++j)
      WxT[(size_t)(n4 + j) * IN_ + k] = f2bf(v[j]);
  } else {
    __shared__ float red[16][64];
    const int n0 = (bid - 24) * 64;             // 12 blocks cover 768 cols
    const int nl = threadIdx.x & 63, kg = threadIdx.x >> 6;   // 16 k-groups
    float m = 1e-30f;
    #pragma unroll
    for (int i = 0; i < 16; ++i)
      m = fmaxf(m, fabsf(Wh[(size_t)(kg * 16 + i) * H3_ + n0 + nl]));
    red[kg][nl] = m;
    __syncthreads();
    if (threadIdx.x < 64) {
      float v = m;                              // kg==0 partial
      #pragma unroll
      for (int i = 1; i < 16; ++i) v = fmaxf(v, red[i][nl]);
      sw[n0 + nl] = v * (1.f / 127.f);
    }
  }
}

// ---------------------------------------------------------------------------
// K2 (prep1): blocks [0,48):   Wh -> whp8 int8 fragment pack (front-loaded),
//   1024-consumer layout (R9-proven): whp8[tp*192 + g*64 + kk*16 + j8*8 + j],
//   n = g*256 + (tp>>6)*16 + (tp&15), k = kk*64 + ((tp>>4)&3)*16 + j8*8 + j.
//             blocks [48,560): gx GEMM, tile 128(M) x 384(N), K=128.
__global__ __launch_bounds__(512) void prep1(const float* __restrict__ x,
                                             const u16* __restrict__ WxT,
                                             const float* __restrict__ bx,
                                             const float* __restrict__ bh,
                                             const float* __restrict__ Wh,
                                             const float* __restrict__ sw,
                                             u16* __restrict__ gxw,
                                             signed char* __restrict__ whp8) {
  __shared__ __align__(16) char smem[(128 * 136 + 384 * 136) * 2];  // 139 KB
  const int bid = blockIdx.x;
  const int tid = threadIdx.x;

  if (bid < 48) {                               // ---- Wh int8 pack ----
    int o8 = bid * 512 + tid;                   // 0..24575 (8 bytes each)
    int j8 = o8 & 1;
    int kk = (o8 >> 1) & 3;
    int g  = (o8 >> 3) % 3;
    int tp = o8 / 24;                           // scan-kernel tid, 0..1023
    int l  = tp & 63, w = tp >> 6;
    int n  = g * 256 + w * 16 + (l & 15);
    int kbase = kk * 64 + ((l >> 4) & 3) * 16 + j8 * 8;
    float rs = rcp_(sw[n]);                     // 127 / max_k|Wh[:,n]|
    c8x8 v;
    #pragma unroll
    for (int j = 0; j < 8; ++j) {
      float q = __builtin_rintf(Wh[(size_t)(kbase + j) * H3_ + n] * rs);
      v[j] = (signed char)(int)q;
    }
    *(c8x8*)(whp8 + (size_t)o8 * 8) = v;
    return;
  }

  // ---- gx GEMM ----
  u16 (*As)[136] = (u16(*)[136])smem;
  u16 (*Bs)[136] = (u16(*)[136])(smem + 128 * 136 * 2);
  u16 (*St)[392] = (u16(*)[392])smem;           // aliases after 2nd barrier

  const int gb = bid - 48;                      // 0..511
  const int mt = gb & 255;
  const int n0 = (gb >> 8) * 384;               // 0 or 384
  const int m0 = mt * 128;
  const int t  = mt >> 1;
  const int brow0 = (mt & 1) * 128;
  const int w = tid >> 6, lane = tid & 63, quad = lane >> 4, r = lane & 15;
  const int wm = w >> 2, wn = w & 3;            // 2 x 4 wave grid

  {  // A tile: 128 rows x 128 cols, f32 -> bf16; 4-lane groups read 64B
    int row = tid >> 2;
    int colc = (tid & 3) * 4;
    const float* s = x + ((size_t)(brow0 + row) * T_ + t) * IN_ + colc;
    #pragma unroll
    for (int c4 = 0; c4 < 8; ++c4) {
      f32x4 v = *(const f32x4*)(s + c4 * 16);
      u16x4 b;
      b[0] = f2bf(v[0]); b[1] = f2bf(v[1]); b[2] = f2bf(v[2]); b[3] = f2bf(v[3]);
      *(u16x4*)&As[row][colc + c4 * 16] = b;
    }
  }
  {  // B tile [n][k] from WxT: 384 x 128 u16
    #pragma unroll
    for (int i = 0; i < 12; ++i) {
      int idx = tid + i * 512;                  // 0..6143
      int row = idx >> 4, col8 = (idx & 15) * 8;
      *(u16x8*)&Bs[row][col8] = *(const u16x8*)(WxT + (size_t)(n0 + row) * IN_ + col8);
    }
  }
  __syncthreads();

  f32x4 acc[4][6];
  #pragma unroll
  for (int i = 0; i < 4; ++i)
    #pragma unroll
    for (int j = 0; j < 6; ++j)
      acc[i][j] = (f32x4){0.f, 0.f, 0.f, 0.f};

  #pragma unroll
  for (int kk = 0; kk < 4; ++kk) {
    bf16x8 a[4];
    #pragma unroll
    for (int m2 = 0; m2 < 4; ++m2)
      a[m2] = *(const bf16x8*)&As[wm * 64 + m2 * 16 + r][kk * 32 + quad * 8];
    #pragma unroll
    for (int n2 = 0; n2 < 6; ++n2) {
      bf16x8 b = *(const bf16x8*)&Bs[wn * 96 + n2 * 16 + r][kk * 32 + quad * 8];
      #pragma unroll
      for (int m2 = 0; m2 < 4; ++m2)
        acc[m2][n2] = mfma16(a[m2], b, acc[m2][n2]);
    }
  }

  __syncthreads();   // all LDS reads done; safe to alias As/Bs as St

  #pragma unroll
  for (int m2 = 0; m2 < 4; ++m2)
    #pragma unroll
    for (int n2 = 0; n2 < 6; ++n2) {
      int nl = wn * 96 + n2 * 16 + r;           // local col (C col = lane&15)
      int n  = n0 + nl;
      float sc = (n < 512) ? L2E : (2.f * L2E);
      float bias = bx[n] + (n < 512 ? bh[n] : 0.f);
      #pragma unroll
      for (int e = 0; e < 4; ++e) {             // C row = quad*4 + e
        int mrow = wm * 64 + m2 * 16 + quad * 4 + e;
        St[mrow][nl] = f2bf((acc[m2][n2][e] + bias) * sc);
      }
    }
  __syncthreads();

  #pragma unroll
  for (int i = 0; i < 12; ++i) {                // coalesced 16B stores
    int idx = tid + i * 512;                    // 0..6143
    int row = idx / 48, c8 = (idx % 48) * 8;
    *(u16x8*)(gxw + (size_t)(m0 + row) * H3_ + n0 + c8) = *(const u16x8*)&St[row][c8];
  }
}

// ---------------------------------------------------------------------------
// K3: the scan, INT8 — R9's proven kernel (93.5us, VGPR 48, no spill).
// 192 blocks x 1024 threads, 4 batch rows/block. Per step: 4 eager
// ds_read_b128 -> 12 MFMA kk-major (3 independent chains) -> unconditional
// gx(t+1) prefetch -> dequant epilogue -> ds_write_b8 -> one barrier.
__global__ __launch_bounds__(1024)
void cru_scan(const float* __restrict__ hid,
              const signed char* __restrict__ whp8,
              const float* __restrict__ sw,
              const float* __restrict__ bh,
              const u16*  __restrict__ gx,
              float* __restrict__ hT) {
  __shared__ __align__(16) signed char h8[2][4][288];   // double buffer, 2.3 KB

  const int bid = blockIdx.x;           // 192 blocks
  const int c   = bid >> 6;             // component 0..2
  const int b0  = (bid & 63) << 2;      // batch row group of 4
  const int tid = threadIdx.x;
  const int lane = tid & 63, quad = lane >> 4, m = lane & 15;
  const int w  = tid >> 6;              // wave 0..15
  const int bb = m & 3;                 // batch row within group
  const int e  = m >> 2;                // kept accumulator element
  const int hcol = w * 16 + quad * 4 + e;   // owned n-col 0..255

  // --- one-time fragment load: 192 B contiguous per thread, coalesced ---
  i32x4 bfr[3][4];
  {
    const signed char* wp = whp8 + (size_t)tid * 192;
    #pragma unroll
    for (int g = 0; g < 3; ++g)
      #pragma unroll
      for (int kk = 0; kk < 4; ++kk)
        bfr[g][kk] = *(const i32x4*)(wp + g * 64 + kk * 16);
  }

  // --- dequant constants: gh = acc * sW/127, then gate prescale ---
  const float dqR = sw[hcol]       * (L2E / 127.f);
  const float dqZ = sw[256 + hcol] * (L2E / 127.f);
  const float dqN = sw[512 + hcol] * (2.f * L2E / 127.f);

  // --- this lane's h element: h[bb][hcol] ---
  const size_t hrow = (size_t)(c * 256 + b0 + bb) * 256 + hcol;
  float hx = hid[hrow];
  h8[0][bb][hcol] = (signed char)(int)__builtin_rintf(fminf(fmaxf(hx, -1.f), 1.f) * 127.f);
  const float bn0 = bh[512 + hcol] * (2.f * L2E);

  const u16* gxp = gx + (size_t)(b0 + bb) * H3_ + hcol;
  const int rbase = bb * 288 + quad * 16;      // B-frag read base (bytes)

  // prefetch t=0 gx values
  u16 xr = gxp[0], xz = gxp[256], xn = gxp[512];
  const u16* gxs = gxp + (size_t)(B_ * H3_);   // points at t+1

  __syncthreads();

  #pragma unroll 2
  for (int t = 0; t < T_; ++t) {
    const int sel = t & 1;

    // A) eager B-frag reads (4 x ds_read_b128, 16 distinct addrs, 4-way
    //    same-address broadcast, 2-way bank aliasing = free)
    const signed char* hb = &h8[sel][0][0];
    i32x4 f0 = *(const i32x4*)(hb + rbase);
    i32x4 f1 = *(const i32x4*)(hb + rbase + 64);
    i32x4 f2 = *(const i32x4*)(hb + rbase + 128);
    i32x4 f3 = *(const i32x4*)(hb + rbase + 192);

    // B) kk-major MFMA: 3 independent accumulator chains interleaved
    __builtin_amdgcn_s_setprio(1);
    i32x4 accR = {0, 0, 0, 0};
    i32x4 accZ = {0, 0, 0, 0};
    i32x4 accN = {0, 0, 0, 0};
    accR = mfma8(bfr[0][0], f0, accR);
    accZ = mfma8(bfr[1][0], f0, accZ);
    accN = mfma8(bfr[2][0], f0, accN);
    accR = mfma8(bfr[0][1], f1, accR);
    accZ = mfma8(bfr[1][1], f1, accZ);
    accN = mfma8(bfr[2][1], f1, accN);
    accR = mfma8(bfr[0][2], f2, accR);
    accZ = mfma8(bfr[1][2], f2, accZ);
    accN = mfma8(bfr[2][2], f2, accN);
    accR = mfma8(bfr[0][3], f3, accR);
    accZ = mfma8(bfr[1][3], f3, accZ);
    accN = mfma8(bfr[2][3], f3, accN);
    __builtin_amdgcn_s_setprio(0);

    // C) unconditional gx(t+1) prefetch (t=127 reads land in mapped ws)
    u16 nxr = gxs[0], nxz = gxs[256], nxn = gxs[512];
    gxs += B_ * H3_;

    // D) r/z sigmoids
    float gR = (float)pick4i(accR, e) * dqR;
    float gZ = (float)pick4i(accZ, e) * dqZ;
    float sr = rcp_(1.f + exp2f_(-(bf2f(xr) + gR)));       // sigmoid
    float sz = rcp_(1.f + exp2f_(-(bf2f(xz) + gZ)));

    // E) tanh + GRU update
    float gN = (float)pick4i(accN, e) * dqN;
    float nv = bf2f(xn) + sr * (gN + bn0);                 // 2*L2E-scaled
    float nn = fmaf(2.f, rcp_(1.f + exp2f_(-nv)), -1.f);   // tanh, inf-safe
    float hv = nn + sz * (hx - nn);
    hx = hv;
    h8[sel ^ 1][bb][hcol] = (signed char)(int)__builtin_rintf(hv * 127.f);
    xr = nxr; xz = nxz; xn = nxn;
    __syncthreads();   // h8[sel^1] ready; orders next-step reads of sel
  }

  hT[hrow] = hx;
}

// ---------------------------------------------------------------------------
// K4: out[b] = elu(sum_c hT[c,b,:] @ Wf + bf); feature[c,:] = mean_b hT
__global__ __launch_bounds__(128) void finalize(const float* __restrict__ hT,
                                                const float* __restrict__ Wf,
                                                const float* __restrict__ bfv,
                                                float* __restrict__ out) {
  __shared__ float hsum[256];
  const int bid = blockIdx.x, tid = threadIdx.x;
  if (bid < 256) {
    const int b = bid;
    for (int k = tid; k < 256; k += 128)
      hsum[k] = hT[((size_t)(0 * 256 + b)) * 256 + k]
              + hT[((size_t)(1 * 256 + b)) * 256 + k]
              + hT[((size_t)(2 * 256 + b)) * 256 + k];
    __syncthreads();
    float acc = bfv[tid];
    #pragma unroll 8
    for (int k = 0; k < 256; ++k)
      acc = fmaf(hsum[k], Wf[(size_t)k * OUT_ + tid], acc);
    float rv = acc > 0.f ? acc : (__expf(acc) - 1.f);
    out[b * OUT_ + tid] = rv;
  } else {
    const int idx = bid - 256;                 // 0..5
    const int c = idx >> 1, j = ((idx & 1) << 7) + tid;
    float sum = 0.f;
    #pragma unroll 4
    for (int b = 0; b < 256; ++b)
      sum += hT[((size_t)(c * 256 + b)) * 256 + j];
    out[B_ * OUT_ + c * 256 + j] = sum * (1.f / 256.f);
  }
}

// ---------------------------------------------------------------------------
extern "C" void kernel_launch(void* const* d_in, const int* in_sizes, int n_in,
                              void* d_out, int out_size, void* d_ws, size_t ws_size,
                              hipStream_t stream) {
  const float* x   = (const float*)d_in[0];
  const float* hid = (const float*)d_in[1];
  const float* Wx  = (const float*)d_in[2];
  const float* bx  = (const float*)d_in[3];
  const float* Wh  = (const float*)d_in[4];
  const float* bh  = (const float*)d_in[5];
  const float* Wf  = (const float*)d_in[6];
  const float* bf_ = (const float*)d_in[7];
  float* out = (float*)d_out;

  char* ws = (char*)d_ws;
  u16* WxT   = (u16*)ws;                                   // 768*128 bf16 = 192 KiB
  u16* gxw   = (u16*)(ws + (1 << 18));                     // 48 MiB
  size_t off = (1 << 18) + (size_t)T_ * B_ * H3_ * 2;
  float* hTw = (float*)(ws + off);                         // 3*256*256 f32 = 768 KiB
  off += (size_t)3 * 256 * 256 * 4;
  signed char* whp8 = (signed char*)(ws + off);            // 1024*192 = 192 KiB
  off += (size_t)1024 * 192;
  float* sww = (float*)(ws + off);                         // 768 f32

  prep0<<<36, 1024, 0, stream>>>(Wx, Wh, WxT, sww);
  prep1<<<560, 512, 0, stream>>>(x, WxT, bx, bh, Wh, sww, gxw, whp8);
  cru_scan<<<192, 1024, 0, stream>>>(hid, whp8, sww, bh, gxw, hTw);
  finalize<<<262, 128, 0, stream>>>(hTw, Wf, bf_, out);
}